// Round 11
// baseline (70.794 us; speedup 1.0000x reference)
//
#include <hip/hip_runtime.h>

#define ALPHA 0.2f

constexpr int N = 1024;
constexpr int F = 64;
constexpr int TI = 4;          // rows per block in k2
constexpr int NT = 1024;       // k2 threads, 16 waves
constexpr int NW = NT / 64;

// K1e: e1 = h@(W@a1), e2 = h@(W@a2). No Wh materialization (k2 uses (att@h)@W).
__global__ __launch_bounds__(256) void k1e(const float* __restrict__ h,
                                           const float* __restrict__ W,
                                           const float* __restrict__ a,
                                           float* __restrict__ e1,
                                           float* __restrict__ e2) {
    const int t = threadIdx.x;
    __shared__ float w1s[F], w2s[F];

    // w1 = W@a1, w2 = W@a2: thread t covers row f = t>>2, 16 cols
    {
        const int f = t >> 2;
        const int c0 = (t & 3) * 16;
        float s1 = 0.f, s2 = 0.f;
        #pragma unroll
        for (int q = 0; q < 4; ++q) {
            const float4 wv  = *(const float4*)&W[f * F + c0 + q * 4];
            const float4 a1v = *(const float4*)&a[c0 + q * 4];
            const float4 a2v = *(const float4*)&a[F + c0 + q * 4];
            s1 += wv.x*a1v.x + wv.y*a1v.y + wv.z*a1v.z + wv.w*a1v.w;
            s2 += wv.x*a2v.x + wv.y*a2v.y + wv.z*a2v.z + wv.w*a2v.w;
        }
        s1 += __shfl_down(s1, 2); s1 += __shfl_down(s1, 1);
        s2 += __shfl_down(s2, 2); s2 += __shfl_down(s2, 1);
        if ((t & 3) == 0) { w1s[f] = s1; w2s[f] = s2; }
    }
    __syncthreads();

    // wave w -> row i = blockIdx*4 + w; two dots of length 64
    const int wave = t >> 6;
    const int lane = t & 63;
    const int i = blockIdx.x * 4 + wave;
    const float hv = h[(size_t)i * F + lane];
    float v1 = hv * w1s[lane];
    float v2 = hv * w2s[lane];
    #pragma unroll
    for (int off = 32; off > 0; off >>= 1) {
        v1 += __shfl_down(v1, off);
        v2 += __shfl_down(v2, off);
    }
    if (lane == 0) {
        e1[i] = v1;
        e2[i] = v2;
    }
}

// K2e: TI rows/block, no-max softmax; u = att@h; out = elu(u@W).
// Sweep B uses jj/fq lane mapping: each wave load = contiguous 1 KB dwordx4
// (4 rows x 256 B) -> 16 float4 loads/thread instead of 64 scalar.
__global__ __launch_bounds__(NT) void k2e(const int* __restrict__ adj,
                                          const float* __restrict__ h,
                                          const float* __restrict__ W,
                                          const float* __restrict__ e1,
                                          const float* __restrict__ e2,
                                          float* __restrict__ out) {
    const int i0 = blockIdx.x * TI;
    const int t = threadIdx.x;       // 0..1023
    const int wave = t >> 6;         // 0..15
    const int lane = t & 63;

    __shared__ float e2s[N];              // 4 KB
    __shared__ float e1s[TI];
    __shared__ float p[TI][N];            // 16 KB exp-weights
    __shared__ float accs[NW][TI][F];     // 16 KB
    __shared__ float redsum[NW];          // wave w owns row w>>2
    __shared__ float us[TI][F];           // 1 KB

    // ---- adj prefetch: one int4 per thread, issued before any wait ----
    const int r = t >> 8;                // 0..3 (wave-uniform)
    const int j4 = (t & 255) * 4;
    const int4 av = *(const int4*)&adj[(size_t)(i0 + r) * N + j4];

    e2s[t] = e2[t];
    if (t < TI) e1s[t] = e1[i0 + t];
    __syncthreads();

    // ---- sweep A: p[r][j] = adj ? exp(leaky(e1+e2)) : 0, + row sums ----
    {
        const float e1r = e1s[r];
        const float4 ev = *(const float4*)&e2s[j4];
        float4 pe;
        float s;
        s = e1r + ev.x; s = (s > 0.f) ? s : ALPHA * s; pe.x = (av.x > 0) ? __expf(s) : 0.f;
        s = e1r + ev.y; s = (s > 0.f) ? s : ALPHA * s; pe.y = (av.y > 0) ? __expf(s) : 0.f;
        s = e1r + ev.z; s = (s > 0.f) ? s : ALPHA * s; pe.z = (av.z > 0) ? __expf(s) : 0.f;
        s = e1r + ev.w; s = (s > 0.f) ? s : ALPHA * s; pe.w = (av.w > 0) ? __expf(s) : 0.f;
        *(float4*)&p[r][j4] = pe;
        float ls = (pe.x + pe.y) + (pe.z + pe.w);
        #pragma unroll
        for (int off = 32; off > 0; off >>= 1) ls += __shfl_down(ls, off);
        if (lane == 0) redsum[wave] = ls;     // partial for row wave>>2
    }
    __syncthreads();

    // ---- sweep B: u[r][f] += sum_j p[r][j]*h[j][f]; wave w covers 64 j.
    //      lane = jj(2b)|fq(4b): load h[j0+4i+jj][4fq..4fq+3] -> the wave's
    //      16 B x 64 lanes = one contiguous 1 KB transaction. ----
    {
        const int jj = lane >> 4;        // 0..3
        const int fq = lane & 15;        // feature quad
        float4 u0 = {0,0,0,0}, u1 = {0,0,0,0}, u2 = {0,0,0,0}, u3 = {0,0,0,0};
        const int j0 = wave * 64;
        #pragma unroll 4
        for (int it = 0; it < 16; ++it) {
            const int j = j0 + it * 4 + jj;
            const float4 hv = *(const float4*)&h[(size_t)j * F + fq * 4];
            const float p0 = p[0][j];    // 16-lane LDS broadcast each
            const float p1 = p[1][j];
            const float p2 = p[2][j];
            const float p3 = p[3][j];
            u0.x += p0 * hv.x; u0.y += p0 * hv.y; u0.z += p0 * hv.z; u0.w += p0 * hv.w;
            u1.x += p1 * hv.x; u1.y += p1 * hv.y; u1.z += p1 * hv.z; u1.w += p1 * hv.w;
            u2.x += p2 * hv.x; u2.y += p2 * hv.y; u2.z += p2 * hv.z; u2.w += p2 * hv.w;
            u3.x += p3 * hv.x; u3.y += p3 * hv.y; u3.z += p3 * hv.z; u3.w += p3 * hv.w;
        }
        // fold jj (4 groups of 16 lanes): after these, lanes 0..15 hold full sums
        #pragma unroll
        for (int off = 32; off >= 16; off >>= 1) {
            #pragma unroll
            for (int c = 0; c < 4; ++c) {
                (&u0.x)[c] += __shfl_down((&u0.x)[c], off);
                (&u1.x)[c] += __shfl_down((&u1.x)[c], off);
                (&u2.x)[c] += __shfl_down((&u2.x)[c], off);
                (&u3.x)[c] += __shfl_down((&u3.x)[c], off);
            }
        }
        if (lane < 16) {
            *(float4*)&accs[wave][0][fq * 4] = u0;
            *(float4*)&accs[wave][1][fq * 4] = u1;
            *(float4*)&accs[wave][2][fq * 4] = u2;
            *(float4*)&accs[wave][3][fq * 4] = u3;
        }
    }
    __syncthreads();

    // ---- epilogue A: reduce 16 waves, normalize -> us ----
    if (t < TI * F) {
        const int rr = t >> 6;
        const int f = t & 63;
        float su = 0.f;
        #pragma unroll
        for (int w = 0; w < NW; ++w) su += accs[w][rr][f];
        const float dn = redsum[4*rr] + redsum[4*rr+1] + redsum[4*rr+2] + redsum[4*rr+3];
        us[rr][f] = su / dn;
    }
    __syncthreads();

    // ---- epilogue B: out[r][g] = elu( us[r][:] @ W[:][g] ) ----
    if (t < TI * F) {
        const int rr = t >> 6;
        const int g = t & 63;
        float acc = 0.f;
        #pragma unroll
        for (int f = 0; f < F; ++f)
            acc += us[rr][f] * W[f * F + g];   // us: wave-uniform broadcast; W coalesced
        out[(size_t)(i0 + rr) * F + g] = (acc > 0.f) ? acc : expm1f(acc);
    }
}

extern "C" void kernel_launch(void* const* d_in, const int* in_sizes, int n_in,
                              void* d_out, int out_size, void* d_ws, size_t ws_size,
                              hipStream_t stream) {
    const float* h   = (const float*)d_in[0];
    const int*   adj = (const int*)d_in[1];
    const float* W   = (const float*)d_in[2];
    const float* a   = (const float*)d_in[3];
    float* out       = (float*)d_out;

    float* ws = (float*)d_ws;
    float* e1 = ws;        // N floats
    float* e2 = ws + N;    // N floats

    k1e<<<256, 256, 0, stream>>>(h, W, a, e1, e2);
    k2e<<<N / TI, NT, 0, stream>>>(adj, h, W, e1, e2, out);
}

// Round 12
// 69.899 us; speedup vs baseline: 1.0128x; 1.0128x over previous
//
#include <hip/hip_runtime.h>

#define ALPHA 0.2f

constexpr int N = 1024;
constexpr int F = 64;
constexpr int TI = 4;          // rows per block in k2
constexpr int NT = 1024;       // k2 threads, 16 waves
constexpr int NW = NT / 64;

// K1e: e1 = h@(W@a1), e2 = h@(W@a2). No Wh materialization (k2 uses (att@h)@W).
// grid: 256 blocks x 256 threads; each block: redundant tiny w1/w2, then 4 rows.
__global__ __launch_bounds__(256) void k1e(const float* __restrict__ h,
                                           const float* __restrict__ W,
                                           const float* __restrict__ a,
                                           float* __restrict__ e1,
                                           float* __restrict__ e2) {
    const int t = threadIdx.x;
    __shared__ float w1s[F], w2s[F];

    // w1 = W@a1, w2 = W@a2: thread t covers row f = t>>2, 16 cols
    {
        const int f = t >> 2;
        const int c0 = (t & 3) * 16;
        float s1 = 0.f, s2 = 0.f;
        #pragma unroll
        for (int q = 0; q < 4; ++q) {
            const float4 wv  = *(const float4*)&W[f * F + c0 + q * 4];
            const float4 a1v = *(const float4*)&a[c0 + q * 4];
            const float4 a2v = *(const float4*)&a[F + c0 + q * 4];
            s1 += wv.x*a1v.x + wv.y*a1v.y + wv.z*a1v.z + wv.w*a1v.w;
            s2 += wv.x*a2v.x + wv.y*a2v.y + wv.z*a2v.z + wv.w*a2v.w;
        }
        s1 += __shfl_down(s1, 2); s1 += __shfl_down(s1, 1);
        s2 += __shfl_down(s2, 2); s2 += __shfl_down(s2, 1);
        if ((t & 3) == 0) { w1s[f] = s1; w2s[f] = s2; }
    }
    __syncthreads();

    // wave w -> row i = blockIdx*4 + w; two dots of length 64
    const int wave = t >> 6;
    const int lane = t & 63;
    const int i = blockIdx.x * 4 + wave;
    const float hv = h[(size_t)i * F + lane];
    float v1 = hv * w1s[lane];
    float v2 = hv * w2s[lane];
    #pragma unroll
    for (int off = 32; off > 0; off >>= 1) {
        v1 += __shfl_down(v1, off);
        v2 += __shfl_down(v2, off);
    }
    if (lane == 0) {
        e1[i] = v1;
        e2[i] = v2;
    }
}

// K2e: TI rows/block, no-max softmax; u = att@h; out = elu(u@W).
__global__ __launch_bounds__(NT) void k2e(const int* __restrict__ adj,
                                          const float* __restrict__ h,
                                          const float* __restrict__ W,
                                          const float* __restrict__ e1,
                                          const float* __restrict__ e2,
                                          float* __restrict__ out) {
    const int i0 = blockIdx.x * TI;
    const int t = threadIdx.x;       // 0..1023
    const int wave = t >> 6;         // 0..15
    const int lane = t & 63;

    __shared__ float e2s[N];              // 4 KB
    __shared__ float e1s[TI];
    __shared__ float p[TI][N];            // 16 KB exp-weights
    __shared__ float accs[NW][TI][F];     // 16 KB
    __shared__ float redsum[NW];          // wave w owns row w>>2
    __shared__ float us[TI][F];           // 1 KB

    // ---- adj prefetch: one int4 per thread, issued before any wait ----
    const int r = t >> 8;                // 0..3 (wave-uniform: r = wave>>2)
    const int j4 = (t & 255) * 4;
    const int4 av = *(const int4*)&adj[(size_t)(i0 + r) * N + j4];

    e2s[t] = e2[t];
    if (t < TI) e1s[t] = e1[i0 + t];
    __syncthreads();

    // ---- sweep A: p[r][j] = adj ? exp(leaky(e1+e2)) : 0, + row sums ----
    {
        const float e1r = e1s[r];
        const float4 ev = *(const float4*)&e2s[j4];
        float4 pe;
        float s;
        s = e1r + ev.x; s = (s > 0.f) ? s : ALPHA * s; pe.x = (av.x > 0) ? __expf(s) : 0.f;
        s = e1r + ev.y; s = (s > 0.f) ? s : ALPHA * s; pe.y = (av.y > 0) ? __expf(s) : 0.f;
        s = e1r + ev.z; s = (s > 0.f) ? s : ALPHA * s; pe.z = (av.z > 0) ? __expf(s) : 0.f;
        s = e1r + ev.w; s = (s > 0.f) ? s : ALPHA * s; pe.w = (av.w > 0) ? __expf(s) : 0.f;
        *(float4*)&p[r][j4] = pe;
        float ls = (pe.x + pe.y) + (pe.z + pe.w);
        #pragma unroll
        for (int off = 32; off > 0; off >>= 1) ls += __shfl_down(ls, off);
        if (lane == 0) redsum[wave] = ls;     // partial for row wave>>2
    }
    __syncthreads();

    // ---- sweep B: u[r][f] += sum_j p[r][j]*h[j][f]; wave w covers 64 j ----
    {
        float a0 = 0.f, a1 = 0.f, a2 = 0.f, a3 = 0.f;
        const int j0 = wave * 64;
        #pragma unroll 4
        for (int j = j0; j < j0 + 64; j += 4) {
            const float4 p0 = *(const float4*)&p[0][j];   // wave-uniform: LDS broadcast
            const float4 p1 = *(const float4*)&p[1][j];
            const float4 p2 = *(const float4*)&p[2][j];
            const float4 p3 = *(const float4*)&p[3][j];
            #pragma unroll
            for (int u = 0; u < 4; ++u) {
                const float hv = h[(size_t)(j + u) * F + lane];  // coalesced, L2-hot
                a0 += (&p0.x)[u] * hv;
                a1 += (&p1.x)[u] * hv;
                a2 += (&p2.x)[u] * hv;
                a3 += (&p3.x)[u] * hv;
            }
        }
        accs[wave][0][lane] = a0;
        accs[wave][1][lane] = a1;
        accs[wave][2][lane] = a2;
        accs[wave][3][lane] = a3;
    }
    __syncthreads();

    // ---- epilogue A: reduce 16 waves, normalize -> us ----
    if (t < TI * F) {
        const int rr = t >> 6;
        const int f = t & 63;
        float su = 0.f;
        #pragma unroll
        for (int w = 0; w < NW; ++w) su += accs[w][rr][f];
        const float dn = redsum[4*rr] + redsum[4*rr+1] + redsum[4*rr+2] + redsum[4*rr+3];
        us[rr][f] = su / dn;
    }
    __syncthreads();

    // ---- epilogue B: out[r][g] = elu( us[r][:] @ W[:][g] ) ----
    if (t < TI * F) {
        const int rr = t >> 6;
        const int g = t & 63;
        float acc = 0.f;
        #pragma unroll
        for (int f = 0; f < F; ++f)
            acc += us[rr][f] * W[f * F + g];   // us: wave-uniform broadcast; W coalesced
        out[(size_t)(i0 + rr) * F + g] = (acc > 0.f) ? acc : expm1f(acc);
    }
}

extern "C" void kernel_launch(void* const* d_in, const int* in_sizes, int n_in,
                              void* d_out, int out_size, void* d_ws, size_t ws_size,
                              hipStream_t stream) {
    const float* h   = (const float*)d_in[0];
    const int*   adj = (const int*)d_in[1];
    const float* W   = (const float*)d_in[2];
    const float* a   = (const float*)d_in[3];
    float* out       = (float*)d_out;

    float* ws = (float*)d_ws;
    float* e1 = ws;        // N floats
    float* e2 = ws + N;    // N floats

    k1e<<<256, 256, 0, stream>>>(h, W, a, e1, e2);
    k2e<<<N / TI, NT, 0, stream>>>(adj, h, W, e1, e2, out);
}